// Round 1
// baseline (2069.171 us; speedup 1.0000x reference)
//
#include <hip/hip_runtime.h>
#include <math.h>

#define BB 4
#define SS 512
#define HIDD 768
#define NHH 12
#define DHH 64

#define ROWS 8   // hidden rows per block in QKV kernel

// ---------------- Kernel 1: QKV projection ----------------
// grid: (B*S/ROWS) blocks, 256 threads.
// Stages ROWS rows of hidden in LDS; thread t computes columns t, t+256, t+512
// for Wq/Wk/Wv simultaneously (W element loads are coalesced across threads and
// reused ROWS times). Writes q,k,v in [B,NH,S,DH] layout.
__global__ __launch_bounds__(256) void qkv_kernel(
    const float* __restrict__ hidden,                       // [B,S,HID]
    const float* __restrict__ Wq, const float* __restrict__ bq,
    const float* __restrict__ Wk, const float* __restrict__ bk,
    const float* __restrict__ Wv, const float* __restrict__ bv,
    float* __restrict__ qo, float* __restrict__ ko, float* __restrict__ vo)
{
    __shared__ float hs[ROWS][HIDD];
    const int row0 = blockIdx.x * ROWS;   // global row = b*S+s
    const int t = threadIdx.x;

    for (int i = t; i < ROWS * HIDD; i += 256) {
        int r = i / HIDD, c = i % HIDD;
        hs[r][c] = hidden[(row0 + r) * HIDD + c];
    }
    __syncthreads();

    for (int jj = 0; jj < 3; ++jj) {
        const int j = t + jj * 256;
        float accq[ROWS], acck[ROWS], accv[ROWS];
#pragma unroll
        for (int r = 0; r < ROWS; ++r) { accq[r] = 0.f; acck[r] = 0.f; accv[r] = 0.f; }

        for (int i = 0; i < HIDD; ++i) {
            float wq = Wq[i * HIDD + j];
            float wk = Wk[i * HIDD + j];
            float wv = Wv[i * HIDD + j];
#pragma unroll
            for (int r = 0; r < ROWS; ++r) {
                float h = hs[r][i];
                accq[r] = fmaf(h, wq, accq[r]);
                acck[r] = fmaf(h, wk, acck[r]);
                accv[r] = fmaf(h, wv, accv[r]);
            }
        }
        const int hh = j / DHH, d = j % DHH;
        const float bqj = bq[j], bkj = bk[j], bvj = bv[j];
#pragma unroll
        for (int r = 0; r < ROWS; ++r) {
            int row = row0 + r;
            int b = row / SS, s = row % SS;
            int idx = ((b * NHH + hh) * SS + s) * DHH + d;
            qo[idx] = accq[r] + bqj;
            ko[idx] = acck[r] + bkj;
            vo[idx] = accv[r] + bvj;
        }
    }
}

// ---------------- Kernel 2: fused relational attention ----------------
// grid: B*S blocks (one per (b, query)), 256 threads (4 waves).
// scores[h][k] = (q[h]·(K[h,k] + rel[q,k])) * 0.125 + mask[b,k]
// softmax per head, then ctx[h][d] = sum_k probs[h][k] * (V[h,k,d] + rel[q,k,d]).
#define KT 64   // k-tile staged in LDS

__global__ __launch_bounds__(256) void attn_kernel(
    const float* __restrict__ q,    // [B,NH,S,DH]
    const float* __restrict__ k,
    const float* __restrict__ v,
    const float* __restrict__ rel,  // [B,S,S,DH]
    const float* __restrict__ mask, // [B,1,1,S]
    float* __restrict__ out)        // [B,S,HID]
{
    __shared__ float scores[NHH][SS];      // 24 KB
    __shared__ float rel_s[KT][DHH + 1];   // 16.6 KB (pad breaks bank conflicts)
    __shared__ float q_s[NHH][DHH];        // 3 KB

    const int bq_idx = blockIdx.x;
    const int b = bq_idx / SS, qi = bq_idx % SS;
    const int t = threadIdx.x;

    for (int i = t; i < NHH * DHH; i += 256) {
        int h = i / DHH, d = i % DHH;
        q_s[h][d] = q[((b * NHH + h) * SS + qi) * DHH + d];
    }
    __syncthreads();

    // ---- Phase A: scores ----
    for (int k0 = 0; k0 < SS; k0 += KT) {
        for (int i = t; i < KT * DHH; i += 256) {
            int kk = i / DHH, d = i % DHH;
            rel_s[kk][d] = rel[((size_t)(b * SS + qi) * SS + (k0 + kk)) * DHH + d];
        }
        __syncthreads();

        // 12 heads x 64 keys = 768 pairs; 3 per thread
#pragma unroll
        for (int pp = 0; pp < 3; ++pp) {
            int p = t + pp * 256;
            int h = p >> 6, kk = p & 63;
            const float* krow = &k[((b * NHH + h) * SS + (k0 + kk)) * DHH];
            float s = 0.f;
#pragma unroll 8
            for (int d = 0; d < DHH; ++d)
                s = fmaf(q_s[h][d], krow[d] + rel_s[kk][d], s);
            scores[h][k0 + kk] = s * 0.125f + mask[b * SS + k0 + kk];
        }
        __syncthreads();
    }

    // ---- Phase B: softmax (wave w handles heads 3w..3w+2) ----
    const int wave = t >> 6, lane = t & 63;
    for (int h = wave * 3; h < wave * 3 + 3; ++h) {
        float m = -1e30f;
        for (int i = lane; i < SS; i += 64) m = fmaxf(m, scores[h][i]);
#pragma unroll
        for (int off = 32; off > 0; off >>= 1) m = fmaxf(m, __shfl_xor(m, off));
        float sum = 0.f;
        for (int i = lane; i < SS; i += 64) {
            float e = __expf(scores[h][i] - m);
            scores[h][i] = e;
            sum += e;
        }
#pragma unroll
        for (int off = 32; off > 0; off >>= 1) sum += __shfl_xor(sum, off);
        float inv = 1.0f / sum;
        for (int i = lane; i < SS; i += 64) scores[h][i] *= inv;
    }
    __syncthreads();

    // ---- Phase C: ctx ----
    float acc[3] = {0.f, 0.f, 0.f};
    for (int k0 = 0; k0 < SS; k0 += KT) {
        for (int i = t; i < KT * DHH; i += 256) {
            int kk = i / DHH, d = i % DHH;
            rel_s[kk][d] = rel[((size_t)(b * SS + qi) * SS + (k0 + kk)) * DHH + d];
        }
        __syncthreads();

#pragma unroll
        for (int pp = 0; pp < 3; ++pp) {
            int p = t + pp * 256;
            int h = p >> 6, d = p & 63;
            const float* vcol = &v[((b * NHH + h) * SS + k0) * DHH + d];
            float a = 0.f;
#pragma unroll 8
            for (int kk = 0; kk < KT; ++kk)
                a = fmaf(scores[h][k0 + kk], vcol[kk * DHH] + rel_s[kk][d], a);
            acc[pp] += a;
        }
        __syncthreads();
    }

#pragma unroll
    for (int pp = 0; pp < 3; ++pp) {
        int p = t + pp * 256;
        int h = p >> 6, d = p & 63;
        out[(size_t)(b * SS + qi) * HIDD + h * DHH + d] = acc[pp];
    }
}

extern "C" void kernel_launch(void* const* d_in, const int* in_sizes, int n_in,
                              void* d_out, int out_size, void* d_ws, size_t ws_size,
                              hipStream_t stream) {
    const float* hidden = (const float*)d_in[0];
    const float* mask   = (const float*)d_in[1];
    const float* rel    = (const float*)d_in[2];
    const float* Wq     = (const float*)d_in[3];
    const float* bq     = (const float*)d_in[4];
    const float* Wk     = (const float*)d_in[5];
    const float* bk     = (const float*)d_in[6];
    const float* Wv     = (const float*)d_in[7];
    const float* bv     = (const float*)d_in[8];
    float* out = (float*)d_out;

    const size_t per = (size_t)BB * NHH * SS * DHH;  // 1.57M floats
    float* qw = (float*)d_ws;
    float* kw = qw + per;
    float* vw = kw + per;

    qkv_kernel<<<BB * SS / ROWS, 256, 0, stream>>>(hidden, Wq, bq, Wk, bk, Wv, bv, qw, kw, vw);
    attn_kernel<<<BB * SS, 256, 0, stream>>>(qw, kw, vw, rel, mask, out);
}

// Round 3
// 1102.092 us; speedup vs baseline: 1.8775x; 1.8775x over previous
//
#include <hip/hip_runtime.h>
#include <math.h>

#define BB 4
#define SS 512
#define HIDD 768
#define NHH 12
#define DHH 64

// ======================= K1: QKV projection GEMM =======================
// C[2048 x 768] = hidden[2048 x 768] @ W[768 x 768] (+bias), for W in {Wq,Wk,Wv}.
// 64x64 block tile, 16x16 threads, 4x4 micro-tile, K-step 16.
// Output written head-major: [B,NH,S,DH].
__global__ __launch_bounds__(256) void qkv_gemm(
    const float* __restrict__ hidden,
    const float* __restrict__ Wq, const float* __restrict__ bq,
    const float* __restrict__ Wk, const float* __restrict__ bk,
    const float* __restrict__ Wv, const float* __restrict__ bv,
    float* __restrict__ qo, float* __restrict__ ko, float* __restrict__ vo)
{
    __shared__ float As[16][64];   // [k][m]
    __shared__ float Bs[16][64];   // [k][n]

    const int m0 = blockIdx.x * 64;
    const int wsel = blockIdx.y / 12;
    const int n0 = (blockIdx.y % 12) * 64;
    const float* __restrict__ W    = (wsel == 0) ? Wq : (wsel == 1) ? Wk : Wv;
    const float* __restrict__ bias = (wsel == 0) ? bq : (wsel == 1) ? bk : bv;
    float* __restrict__ out        = (wsel == 0) ? qo : (wsel == 1) ? ko : vo;

    const int t = threadIdx.x;
    const int tx = t & 15, ty = t >> 4;
    const int am = t >> 2, afq = t & 3;     // A staging: row am, f4-col afq
    const int bkr = t >> 4, bfn = t & 15;   // B staging: row bkr, f4-col bfn

    float acc[4][4] = {};

    for (int k0 = 0; k0 < HIDD; k0 += 16) {
        float4 av = *(const float4*)&hidden[(m0 + am) * HIDD + k0 + afq * 4];
        float4 bv4 = *(const float4*)&W[(k0 + bkr) * HIDD + n0 + bfn * 4];
        __syncthreads();
        As[afq * 4 + 0][am] = av.x;
        As[afq * 4 + 1][am] = av.y;
        As[afq * 4 + 2][am] = av.z;
        As[afq * 4 + 3][am] = av.w;
        *(float4*)&Bs[bkr][bfn * 4] = bv4;
        __syncthreads();
#pragma unroll
        for (int kk = 0; kk < 16; ++kk) {
            float4 a4 = *(const float4*)&As[kk][ty * 4];
            float4 b4 = *(const float4*)&Bs[kk][tx * 4];
            float a[4] = {a4.x, a4.y, a4.z, a4.w};
            float bb[4] = {b4.x, b4.y, b4.z, b4.w};
#pragma unroll
            for (int r = 0; r < 4; ++r)
#pragma unroll
                for (int c = 0; c < 4; ++c)
                    acc[r][c] = fmaf(a[r], bb[c], acc[r][c]);
        }
    }

    const int b = m0 >> 9;          // 512 rows per batch, tile never straddles
    const int h = n0 >> 6;          // tile spans exactly one head
    float bi[4];
#pragma unroll
    for (int c = 0; c < 4; ++c) bi[c] = bias[n0 + tx * 4 + c];

#pragma unroll
    for (int r = 0; r < 4; ++r) {
        int m = m0 + ty * 4 + r;
        int s = m & (SS - 1);
        float4 o;
        o.x = acc[r][0] + bi[0];
        o.y = acc[r][1] + bi[1];
        o.z = acc[r][2] + bi[2];
        o.w = acc[r][3] + bi[3];
        *(float4*)&out[(((size_t)(b * NHH + h) * SS + s) * DHH) + tx * 4] = o;
    }
}

// ======================= K2: relational score bias =======================
// scores[b,h,q,k] = 0.125 * (q[b,h,q,:] . rel[b,q,k,:]) + mask[b,k]
// One block per (b,q). rel tile (64k x 64d) staged as XOR-swizzled float4.
__global__ __launch_bounds__(256) void relscore_kernel(
    const float* __restrict__ q,     // [B,NH,S,DH]
    const float* __restrict__ rel,   // [B,S,S,DH]
    const float* __restrict__ mask,  // [B,1,1,S]
    float* __restrict__ scores)      // [B,NH,S,S]
{
    __shared__ float4 rel_s[64][16]; // rel_s[kk][f ^ (kk&15)]
    __shared__ float q_s[NHH][DHH];

    const int b = blockIdx.x >> 9, qi = blockIdx.x & (SS - 1);
    const int t = threadIdx.x;

    if (t < NHH * 16) {
        int h = t >> 4, f = t & 15;
        *(float4*)&q_s[h][f * 4] =
            *(const float4*)&q[((size_t)(b * NHH + h) * SS + qi) * DHH + f * 4];
    }

    const float* relrow = rel + (size_t)(b * SS + qi) * SS * DHH;

    for (int k0 = 0; k0 < SS; k0 += 64) {
        __syncthreads();
#pragma unroll
        for (int j = 0; j < 4; ++j) {
            int idx = t + j * 256;
            int kk = idx >> 4, f = idx & 15;
            rel_s[kk][f ^ (kk & 15)] =
                *(const float4*)&relrow[(k0 + kk) * DHH + f * 4];
        }
        __syncthreads();
#pragma unroll
        for (int pp = 0; pp < 3; ++pp) {
            int p = t + pp * 256;
            int h = p >> 6, kk = p & 63;
            float s = 0.f;
#pragma unroll
            for (int f = 0; f < 16; ++f) {
                float4 r4 = rel_s[kk][f ^ (kk & 15)];
                float4 q4 = *(const float4*)&q_s[h][f * 4];
                s = fmaf(q4.x, r4.x, s);
                s = fmaf(q4.y, r4.y, s);
                s = fmaf(q4.z, r4.z, s);
                s = fmaf(q4.w, r4.w, s);
            }
            scores[((size_t)(b * NHH + h) * SS + qi) * SS + k0 + kk] =
                s * 0.125f + mask[b * SS + k0 + kk];
        }
    }
}

// ======================= K3: QK^T + softmax (in place) =======================
// One wave per (b,h,q) row. Lane owns k = {lane + 64j}. K rows stream from L2.
__global__ __launch_bounds__(256) void qk_softmax_kernel(
    const float* __restrict__ q, const float* __restrict__ k,
    float* __restrict__ scores)   // in: relS*0.125+mask; out: P
{
    const int t = threadIdx.x;
    const int wave = t >> 6, lane = t & 63;
    const int gq = blockIdx.x * 4 + wave;      // 0 .. B*NH*S-1
    const int b = gq / (NHH * SS);
    const int rem = gq - b * (NHH * SS);
    const int h = rem >> 9, qi = rem & (SS - 1);

    const float* qrow = q + ((size_t)(b * NHH + h) * SS + qi) * DHH;
    const float* kbase = k + (size_t)(b * NHH + h) * SS * DHH;
    float* srow = scores + ((size_t)(b * NHH + h) * SS + qi) * SS;

    float acc[8];
#pragma unroll
    for (int j = 0; j < 8; ++j) acc[j] = srow[j * 64 + lane];

#pragma unroll
    for (int j = 0; j < 8; ++j) {
        const float* krow = kbase + (size_t)(j * 64 + lane) * DHH;
        float dot = 0.f;
#pragma unroll
        for (int f = 0; f < 16; ++f) {
            float4 k4 = *(const float4*)&krow[f * 4];
            float4 q4 = *(const float4*)&qrow[f * 4];
            dot = fmaf(q4.x, k4.x, dot);
            dot = fmaf(q4.y, k4.y, dot);
            dot = fmaf(q4.z, k4.z, dot);
            dot = fmaf(q4.w, k4.w, dot);
        }
        acc[j] += dot * 0.125f;
    }

    float m = acc[0];
#pragma unroll
    for (int j = 1; j < 8; ++j) m = fmaxf(m, acc[j]);
#pragma unroll
    for (int off = 32; off > 0; off >>= 1) m = fmaxf(m, __shfl_xor(m, off));
    float sum = 0.f;
#pragma unroll
    for (int j = 0; j < 8; ++j) { acc[j] = __expf(acc[j] - m); sum += acc[j]; }
#pragma unroll
    for (int off = 32; off > 0; off >>= 1) sum += __shfl_xor(sum, off);
    float inv = 1.f / sum;
#pragma unroll
    for (int j = 0; j < 8; ++j) srow[j * 64 + lane] = acc[j] * inv;
}

// ======================= K4: ctx1 = P @ V =======================
// One block per (b,h,q-tile-of-32). Writes straight into d_out [B,S,HID].
__global__ __launch_bounds__(256) void pv_kernel(
    const float* __restrict__ P,   // [B,NH,S,S]
    const float* __restrict__ v,   // [B,NH,S,DH]
    float* __restrict__ out)       // [B,S,HID]
{
    __shared__ float Ps[32][64];
    __shared__ float Vs[64][64];

    const int blk = blockIdx.x;
    const int q0 = (blk & 15) * 32;
    const int bh = blk >> 4;
    const int b = bh / NHH, h = bh - b * NHH;
    const int t = threadIdx.x;
    const int d = t & 63, qq = t >> 6;

    const float* Pbase = P + ((size_t)bh * SS + q0) * SS;
    const float* Vbase = v + (size_t)bh * SS * DHH;

    float acc[8] = {};
    for (int k0 = 0; k0 < SS; k0 += 64) {
        __syncthreads();
#pragma unroll
        for (int j = 0; j < 2; ++j) {
            int i = t + j * 256;
            int qr = i >> 4, f = i & 15;
            *(float4*)&Ps[qr][f * 4] = *(const float4*)&Pbase[(size_t)qr * SS + k0 + f * 4];
        }
#pragma unroll
        for (int j = 0; j < 4; ++j) {
            int i = t + j * 256;
            int kr = i >> 4, f = i & 15;
            *(float4*)&Vs[kr][f * 4] = *(const float4*)&Vbase[(size_t)(k0 + kr) * DHH + f * 4];
        }
        __syncthreads();
#pragma unroll
        for (int kk = 0; kk < 64; kk += 4) {
            float v0 = Vs[kk][d], v1 = Vs[kk + 1][d];
            float v2 = Vs[kk + 2][d], v3 = Vs[kk + 3][d];
#pragma unroll
            for (int i = 0; i < 8; ++i) {
                float4 p4 = *(const float4*)&Ps[qq * 8 + i][kk];
                acc[i] = fmaf(p4.x, v0,
                         fmaf(p4.y, v1,
                         fmaf(p4.z, v2,
                         fmaf(p4.w, v3, acc[i]))));
            }
        }
    }
#pragma unroll
    for (int i = 0; i < 8; ++i) {
        int qi = q0 + qq * 8 + i;
        out[((size_t)(b * SS) + qi) * HIDD + h * DHH + d] = acc[i];
    }
}

// ======================= K5: out += P . rel (value bias) =======================
// One block per (b,q). P rows (12x512) + swizzled rel tiles staged in LDS.
__global__ __launch_bounds__(256) void relv_kernel(
    const float* __restrict__ P,    // [B,NH,S,S]
    const float* __restrict__ rel,  // [B,S,S,DH]
    float* __restrict__ out)        // [B,S,HID] accumulate
{
    __shared__ float4 rel_s[64][16];  // swizzled
    __shared__ float Ps[NHH][SS];     // 24 KB

    const int b = blockIdx.x >> 9, qi = blockIdx.x & (SS - 1);
    const int t = threadIdx.x;

#pragma unroll
    for (int j = 0; j < 6; ++j) {
        int i = t + j * 256;          // f4 index into [12][128]
        int h = i >> 7, f = i & 127;
        *(float4*)&Ps[h][f * 4] =
            *(const float4*)&P[((size_t)(b * NHH + h) * SS + qi) * SS + f * 4];
    }

    const float* relrow = rel + (size_t)(b * SS + qi) * SS * DHH;

    float acc[3] = {};
    for (int k0 = 0; k0 < SS; k0 += 64) {
        __syncthreads();
#pragma unroll
        for (int j = 0; j < 4; ++j) {
            int idx = t + j * 256;
            int kk = idx >> 4, f = idx & 15;
            rel_s[kk][f ^ (kk & 15)] =
                *(const float4*)&relrow[(k0 + kk) * DHH + f * 4];
        }
        __syncthreads();
#pragma unroll
        for (int pp = 0; pp < 3; ++pp) {
            int p = t + pp * 256;
            int h = p >> 6, d = p & 63;
            int dhi = d >> 2, dlo = d & 3;
            const float* prow = &Ps[h][k0];
            float a = 0.f;
#pragma unroll
            for (int kk = 0; kk < 64; ++kk) {
                const float* rs = (const float*)&rel_s[kk][0];
                float rv = rs[((dhi ^ (kk & 15)) << 2) | dlo];
                a = fmaf(prow[kk], rv, a);
            }
            acc[pp] += a;
        }
    }

#pragma unroll
    for (int pp = 0; pp < 3; ++pp) {
        int p = t + pp * 256;
        int h = p >> 6, d = p & 63;
        size_t o = ((size_t)(b * SS) + qi) * HIDD + h * DHH + d;
        out[o] += acc[pp];
    }
}

extern "C" void kernel_launch(void* const* d_in, const int* in_sizes, int n_in,
                              void* d_out, int out_size, void* d_ws, size_t ws_size,
                              hipStream_t stream) {
    const float* hidden = (const float*)d_in[0];
    const float* mask   = (const float*)d_in[1];
    const float* rel    = (const float*)d_in[2];
    const float* Wq     = (const float*)d_in[3];
    const float* bq     = (const float*)d_in[4];
    const float* Wk     = (const float*)d_in[5];
    const float* bk     = (const float*)d_in[6];
    const float* Wv     = (const float*)d_in[7];
    const float* bv     = (const float*)d_in[8];
    float* out = (float*)d_out;

    const size_t PER = (size_t)BB * NHH * SS * DHH;   // 1,572,864 floats
    float* qw = (float*)d_ws;
    float* kw = qw + PER;
    float* vw = kw + PER;
    float* sc = vw + PER;                              // [B,NH,S,S] = 12.58M floats

    qkv_gemm<<<dim3(BB * SS / 64, 36), 256, 0, stream>>>(
        hidden, Wq, bq, Wk, bk, Wv, bv, qw, kw, vw);
    relscore_kernel<<<BB * SS, 256, 0, stream>>>(qw, rel, mask, sc);
    qk_softmax_kernel<<<BB * NHH * SS / 4, 256, 0, stream>>>(qw, kw, sc);
    pv_kernel<<<BB * NHH * 16, 256, 0, stream>>>(sc, vw, out);
    relv_kernel<<<BB * SS, 256, 0, stream>>>(sc, rel, out);
}

// Round 4
// 720.766 us; speedup vs baseline: 2.8708x; 1.5291x over previous
//
#include <hip/hip_runtime.h>
#include <math.h>

#define BB 4
#define SS 512
#define HIDD 768
#define NHH 12
#define DHH 64

// ======================= K1: QKV projection GEMM =======================
__global__ __launch_bounds__(256) void qkv_gemm(
    const float* __restrict__ hidden,
    const float* __restrict__ Wq, const float* __restrict__ bq,
    const float* __restrict__ Wk, const float* __restrict__ bk,
    const float* __restrict__ Wv, const float* __restrict__ bv,
    float* __restrict__ qo, float* __restrict__ ko, float* __restrict__ vo)
{
    __shared__ float As[16][64];   // [k][m]
    __shared__ float Bs[16][64];   // [k][n]

    const int m0 = blockIdx.x * 64;
    const int wsel = blockIdx.y / 12;
    const int n0 = (blockIdx.y % 12) * 64;
    const float* __restrict__ W    = (wsel == 0) ? Wq : (wsel == 1) ? Wk : Wv;
    const float* __restrict__ bias = (wsel == 0) ? bq : (wsel == 1) ? bk : bv;
    float* __restrict__ out        = (wsel == 0) ? qo : (wsel == 1) ? ko : vo;

    const int t = threadIdx.x;
    const int tx = t & 15, ty = t >> 4;
    const int am = t >> 2, afq = t & 3;
    const int bkr = t >> 4, bfn = t & 15;

    float acc[4][4] = {};

    for (int k0 = 0; k0 < HIDD; k0 += 16) {
        float4 av = *(const float4*)&hidden[(m0 + am) * HIDD + k0 + afq * 4];
        float4 bv4 = *(const float4*)&W[(k0 + bkr) * HIDD + n0 + bfn * 4];
        __syncthreads();
        As[afq * 4 + 0][am] = av.x;
        As[afq * 4 + 1][am] = av.y;
        As[afq * 4 + 2][am] = av.z;
        As[afq * 4 + 3][am] = av.w;
        *(float4*)&Bs[bkr][bfn * 4] = bv4;
        __syncthreads();
#pragma unroll
        for (int kk = 0; kk < 16; ++kk) {
            float4 a4 = *(const float4*)&As[kk][ty * 4];
            float4 b4 = *(const float4*)&Bs[kk][tx * 4];
            float a[4] = {a4.x, a4.y, a4.z, a4.w};
            float bb[4] = {b4.x, b4.y, b4.z, b4.w};
#pragma unroll
            for (int r = 0; r < 4; ++r)
#pragma unroll
                for (int c = 0; c < 4; ++c)
                    acc[r][c] = fmaf(a[r], bb[c], acc[r][c]);
        }
    }

    const int b = m0 >> 9;
    const int h = n0 >> 6;
    float bi[4];
#pragma unroll
    for (int c = 0; c < 4; ++c) bi[c] = bias[n0 + tx * 4 + c];

#pragma unroll
    for (int r = 0; r < 4; ++r) {
        int m = m0 + ty * 4 + r;
        int s = m & (SS - 1);
        float4 o;
        o.x = acc[r][0] + bi[0];
        o.y = acc[r][1] + bi[1];
        o.z = acc[r][2] + bi[2];
        o.w = acc[r][3] + bi[3];
        *(float4*)&out[(((size_t)(b * NHH + h) * SS + s) * DHH) + tx * 4] = o;
    }
}

// ======================= K2: relational score bias =======================
// scores[b,h,q,k] = 0.125 * (q[b,h,q,:] . rel[b,q,k,:]) + mask[b,k]
__global__ __launch_bounds__(256) void relscore_kernel(
    const float* __restrict__ q,     // [B,NH,S,DH]
    const float* __restrict__ rel,   // [B,S,S,DH]
    const float* __restrict__ mask,  // [B,1,1,S]
    float* __restrict__ scores)      // [B,NH,S,S]
{
    __shared__ float4 rel_s[64][16]; // rel_s[kk][f ^ (kk&15)]
    __shared__ float q_s[NHH][DHH];

    const int b = blockIdx.x >> 9, qi = blockIdx.x & (SS - 1);
    const int t = threadIdx.x;

    if (t < NHH * 16) {
        int h = t >> 4, f = t & 15;
        *(float4*)&q_s[h][f * 4] =
            *(const float4*)&q[((size_t)(b * NHH + h) * SS + qi) * DHH + f * 4];
    }

    const float* relrow = rel + (size_t)(b * SS + qi) * SS * DHH;

    for (int k0 = 0; k0 < SS; k0 += 64) {
        __syncthreads();
#pragma unroll
        for (int j = 0; j < 4; ++j) {
            int idx = t + j * 256;
            int kk = idx >> 4, f = idx & 15;
            rel_s[kk][f ^ (kk & 15)] =
                *(const float4*)&relrow[(k0 + kk) * DHH + f * 4];
        }
        __syncthreads();
#pragma unroll
        for (int pp = 0; pp < 3; ++pp) {
            int p = t + pp * 256;
            int h = p >> 6, kk = p & 63;
            float s = 0.f;
#pragma unroll
            for (int f = 0; f < 16; ++f) {
                float4 r4 = rel_s[kk][f ^ (kk & 15)];
                float4 q4 = *(const float4*)&q_s[h][f * 4];
                s = fmaf(q4.x, r4.x, s);
                s = fmaf(q4.y, r4.y, s);
                s = fmaf(q4.z, r4.z, s);
                s = fmaf(q4.w, r4.w, s);
            }
            scores[((size_t)(b * NHH + h) * SS + qi) * SS + k0 + kk] =
                s * 0.125f + mask[b * SS + k0 + kk];
        }
    }
}

// ======================= K3: scores += 0.125 * Q K^T (batched tiled GEMM) ===
// grid: 48 bh * 64 tiles. Block tile 64q x 64k, d = 64 (full). 4x4 micro-tile.
// Q,K staged [d][q]/[d][k] with pad 68 (2-way bank aliasing = free, 16B aligned).
__global__ __launch_bounds__(256) void qk_add_kernel(
    const float* __restrict__ q, const float* __restrict__ k,
    float* __restrict__ scores)
{
    __shared__ float Qs[64][68];
    __shared__ float Ks[64][68];

    const int bh = blockIdx.x >> 6;
    const int tile = blockIdx.x & 63;
    const int q0 = (tile >> 3) * 64, k0 = (tile & 7) * 64;
    const int t = threadIdx.x;
    const int r = t >> 2, fq = t & 3;

    const float* Qbase = q + ((size_t)bh * SS + q0) * DHH;
    const float* Kbase = k + ((size_t)bh * SS + k0) * DHH;
#pragma unroll
    for (int jj = 0; jj < 4; ++jj) {
        int f = fq + jj * 4;
        float4 a = *(const float4*)&Qbase[r * DHH + f * 4];
        float4 b = *(const float4*)&Kbase[r * DHH + f * 4];
        int d = f * 4;
        Qs[d + 0][r] = a.x; Qs[d + 1][r] = a.y; Qs[d + 2][r] = a.z; Qs[d + 3][r] = a.w;
        Ks[d + 0][r] = b.x; Ks[d + 1][r] = b.y; Ks[d + 2][r] = b.z; Ks[d + 3][r] = b.w;
    }
    __syncthreads();

    const int tx = t & 15, ty = t >> 4;
    float acc[4][4] = {};
#pragma unroll 8
    for (int d = 0; d < 64; ++d) {
        float4 a4 = *(const float4*)&Qs[d][ty * 4];
        float4 b4 = *(const float4*)&Ks[d][tx * 4];
        float a[4] = {a4.x, a4.y, a4.z, a4.w};
        float bb[4] = {b4.x, b4.y, b4.z, b4.w};
#pragma unroll
        for (int rr = 0; rr < 4; ++rr)
#pragma unroll
            for (int cc = 0; cc < 4; ++cc)
                acc[rr][cc] = fmaf(a[rr], bb[cc], acc[rr][cc]);
    }

    // RMW epilogue: scores tile += acc * 0.125
#pragma unroll
    for (int rr = 0; rr < 4; ++rr) {
        float* srow = scores + ((size_t)bh * SS + q0 + ty * 4 + rr) * SS + k0 + tx * 4;
        float4 s = *(const float4*)srow;
        s.x += acc[rr][0] * 0.125f;
        s.y += acc[rr][1] * 0.125f;
        s.z += acc[rr][2] * 0.125f;
        s.w += acc[rr][3] * 0.125f;
        *(float4*)srow = s;
    }
}

// ======================= K4: softmax (in place, streaming) =======================
// One wave per (b,h,q) row; lane owns 8 contiguous floats (2x float4).
__global__ __launch_bounds__(256) void softmax_kernel(float* __restrict__ scores)
{
    const int t = threadIdx.x;
    const int wave = t >> 6, lane = t & 63;
    const size_t row = (size_t)blockIdx.x * 4 + wave;
    float* srow = scores + row * SS;

    float4 v0 = *(const float4*)&srow[lane * 8];
    float4 v1 = *(const float4*)&srow[lane * 8 + 4];
    float a[8] = {v0.x, v0.y, v0.z, v0.w, v1.x, v1.y, v1.z, v1.w};

    float m = a[0];
#pragma unroll
    for (int j = 1; j < 8; ++j) m = fmaxf(m, a[j]);
#pragma unroll
    for (int off = 32; off > 0; off >>= 1) m = fmaxf(m, __shfl_xor(m, off));
    float sum = 0.f;
#pragma unroll
    for (int j = 0; j < 8; ++j) { a[j] = __expf(a[j] - m); sum += a[j]; }
#pragma unroll
    for (int off = 32; off > 0; off >>= 1) sum += __shfl_xor(sum, off);
    float inv = 1.f / sum;

    v0.x = a[0] * inv; v0.y = a[1] * inv; v0.z = a[2] * inv; v0.w = a[3] * inv;
    v1.x = a[4] * inv; v1.y = a[5] * inv; v1.z = a[6] * inv; v1.w = a[7] * inv;
    *(float4*)&srow[lane * 8] = v0;
    *(float4*)&srow[lane * 8 + 4] = v1;
}

// ======================= K5: ctx1 = P @ V =======================
__global__ __launch_bounds__(256) void pv_kernel(
    const float* __restrict__ P,   // [B,NH,S,S]
    const float* __restrict__ v,   // [B,NH,S,DH]
    float* __restrict__ out)       // [B,S,HID]
{
    __shared__ float Ps[32][64];
    __shared__ float Vs[64][64];

    const int blk = blockIdx.x;
    const int q0 = (blk & 15) * 32;
    const int bh = blk >> 4;
    const int b = bh / NHH, h = bh - b * NHH;
    const int t = threadIdx.x;
    const int d = t & 63, qq = t >> 6;

    const float* Pbase = P + ((size_t)bh * SS + q0) * SS;
    const float* Vbase = v + (size_t)bh * SS * DHH;

    float acc[8] = {};
    for (int k0 = 0; k0 < SS; k0 += 64) {
        __syncthreads();
#pragma unroll
        for (int j = 0; j < 2; ++j) {
            int i = t + j * 256;
            int qr = i >> 4, f = i & 15;
            *(float4*)&Ps[qr][f * 4] = *(const float4*)&Pbase[(size_t)qr * SS + k0 + f * 4];
        }
#pragma unroll
        for (int j = 0; j < 4; ++j) {
            int i = t + j * 256;
            int kr = i >> 4, f = i & 15;
            *(float4*)&Vs[kr][f * 4] = *(const float4*)&Vbase[(size_t)(k0 + kr) * DHH + f * 4];
        }
        __syncthreads();
#pragma unroll
        for (int kk = 0; kk < 64; kk += 4) {
            float v0 = Vs[kk][d], v1 = Vs[kk + 1][d];
            float v2 = Vs[kk + 2][d], v3 = Vs[kk + 3][d];
#pragma unroll
            for (int i = 0; i < 8; ++i) {
                float4 p4 = *(const float4*)&Ps[qq * 8 + i][kk];
                acc[i] = fmaf(p4.x, v0,
                         fmaf(p4.y, v1,
                         fmaf(p4.z, v2,
                         fmaf(p4.w, v3, acc[i]))));
            }
        }
    }
#pragma unroll
    for (int i = 0; i < 8; ++i) {
        int qi = q0 + qq * 8 + i;
        out[((size_t)(b * SS) + qi) * HIDD + h * DHH + d] = acc[i];
    }
}

// ======================= K6: out += P . rel (value bias) =======================
__global__ __launch_bounds__(256) void relv_kernel(
    const float* __restrict__ P,    // [B,NH,S,S]
    const float* __restrict__ rel,  // [B,S,S,DH]
    float* __restrict__ out)        // [B,S,HID] accumulate
{
    __shared__ float4 rel_s[64][16];  // swizzled
    __shared__ float Ps[NHH][SS];     // 24 KB

    const int b = blockIdx.x >> 9, qi = blockIdx.x & (SS - 1);
    const int t = threadIdx.x;

#pragma unroll
    for (int j = 0; j < 6; ++j) {
        int i = t + j * 256;
        int h = i >> 7, f = i & 127;
        *(float4*)&Ps[h][f * 4] =
            *(const float4*)&P[((size_t)(b * NHH + h) * SS + qi) * SS + f * 4];
    }

    const float* relrow = rel + (size_t)(b * SS + qi) * SS * DHH;

    float acc[3] = {};
    for (int k0 = 0; k0 < SS; k0 += 64) {
        __syncthreads();
#pragma unroll
        for (int j = 0; j < 4; ++j) {
            int idx = t + j * 256;
            int kk = idx >> 4, f = idx & 15;
            rel_s[kk][f ^ (kk & 15)] =
                *(const float4*)&relrow[(k0 + kk) * DHH + f * 4];
        }
        __syncthreads();
#pragma unroll
        for (int pp = 0; pp < 3; ++pp) {
            int p = t + pp * 256;
            int h = p >> 6, d = p & 63;
            int dhi = d >> 2, dlo = d & 3;
            const float* prow = &Ps[h][k0];
            float a = 0.f;
#pragma unroll
            for (int kk = 0; kk < 64; ++kk) {
                const float* rs = (const float*)&rel_s[kk][0];
                float rv = rs[((dhi ^ (kk & 15)) << 2) | dlo];
                a = fmaf(prow[kk], rv, a);
            }
            acc[pp] += a;
        }
    }

#pragma unroll
    for (int pp = 0; pp < 3; ++pp) {
        int p = t + pp * 256;
        int h = p >> 6, d = p & 63;
        size_t o = ((size_t)(b * SS) + qi) * HIDD + h * DHH + d;
        out[o] += acc[pp];
    }
}

extern "C" void kernel_launch(void* const* d_in, const int* in_sizes, int n_in,
                              void* d_out, int out_size, void* d_ws, size_t ws_size,
                              hipStream_t stream) {
    const float* hidden = (const float*)d_in[0];
    const float* mask   = (const float*)d_in[1];
    const float* rel    = (const float*)d_in[2];
    const float* Wq     = (const float*)d_in[3];
    const float* bq     = (const float*)d_in[4];
    const float* Wk     = (const float*)d_in[5];
    const float* bk     = (const float*)d_in[6];
    const float* Wv     = (const float*)d_in[7];
    const float* bv     = (const float*)d_in[8];
    float* out = (float*)d_out;

    const size_t PER = (size_t)BB * NHH * SS * DHH;   // 1,572,864 floats
    float* qw = (float*)d_ws;
    float* kw = qw + PER;
    float* vw = kw + PER;
    float* sc = vw + PER;                              // [B,NH,S,S]

    qkv_gemm<<<dim3(BB * SS / 64, 36), 256, 0, stream>>>(
        hidden, Wq, bq, Wk, bk, Wv, bv, qw, kw, vw);
    relscore_kernel<<<BB * SS, 256, 0, stream>>>(qw, rel, mask, sc);
    qk_add_kernel<<<BB * NHH * 64, 256, 0, stream>>>(qw, kw, sc);
    softmax_kernel<<<BB * NHH * SS / 4, 256, 0, stream>>>(sc);
    pv_kernel<<<BB * NHH * 16, 256, 0, stream>>>(sc, vw, out);
    relv_kernel<<<BB * SS, 256, 0, stream>>>(sc, rel, out);
}